// Round 1
// baseline (1347.249 us; speedup 1.0000x reference)
//
#include <hip/hip_runtime.h>
#include <hip/hip_bf16.h>

#define HD 64
#define NODE_DIM 5
#define NEG_SLOPE 0.2f

// exact float atomic max via int tricks (valid for non-NaN values)
__device__ __forceinline__ void atomicMaxF(float* addr, float val) {
    if (val >= 0.0f) {
        atomicMax((int*)addr, __float_as_int(val));
    } else {
        atomicMin((unsigned int*)addr, (unsigned int)__float_as_int(val));
    }
}

// h0[n,d] = sum_k x[n,k]*W[k,d] + b[d]
__global__ void embed_k(const float* __restrict__ x, const float* __restrict__ W,
                        const float* __restrict__ b, float* __restrict__ h, int N) {
    int idx = blockIdx.x * blockDim.x + threadIdx.x;
    if (idx >= N * HD) return;
    int n = idx >> 6, d = idx & 63;
    float acc = b[d];
#pragma unroll
    for (int k = 0; k < NODE_DIM; k++) acc += x[n * NODE_DIM + k] * W[k * HD + d];
    h[idx] = acc;
}

// wave-per-node: hout[n,:] = pre(hin[n,:]) @ W ; alpha_s[n]=hout.a_src ; alpha_d[n]=hout.a_dst
// PRE: apply relu(x + preb) to the input row first (lazy bias+relu from previous layer)
template <bool PRE>
__global__ void gemm_alpha_k(const float* __restrict__ hin, const float* __restrict__ preb,
                             const float* __restrict__ W, const float* __restrict__ asrc,
                             const float* __restrict__ adst, float* __restrict__ hout,
                             float* __restrict__ alpha_s, float* __restrict__ alpha_d, int N) {
    int wave = (int)((blockIdx.x * blockDim.x + threadIdx.x) >> 6);
    int lane = threadIdx.x & 63;
    if (wave >= N) return;
    float hv = hin[(size_t)wave * HD + lane];
    if (PRE) hv = fmaxf(hv + preb[lane], 0.0f);
    float acc = 0.0f;
#pragma unroll
    for (int k = 0; k < HD; k++) {
        acc += __shfl(hv, k) * W[k * HD + lane];
    }
    hout[(size_t)wave * HD + lane] = acc;
    float ps = acc * asrc[lane];
    float pd = acc * adst[lane];
#pragma unroll
    for (int off = 32; off; off >>= 1) {
        ps += __shfl_xor(ps, off);
        pd += __shfl_xor(pd, off);
    }
    if (lane == 0) {
        alpha_s[wave] = ps;
        alpha_d[wave] = pd;
    }
}

// zero the accumulator buffer, init m=-inf, denom=0
__global__ void init_k(float* __restrict__ bufA, float* __restrict__ m,
                       float* __restrict__ denom, int NH, int N) {
    int i = blockIdx.x * blockDim.x + threadIdx.x;
    if (i < NH) bufA[i] = 0.0f;
    if (i < N) {
        m[i] = -INFINITY;
        denom[i] = 0.0f;
    }
}

// pass 1: e = leaky_relu(as[src] + ad[dst]); store e; m[dst] = max(m[dst], e)
__global__ void edge1_k(const int* __restrict__ ei, const float* __restrict__ as,
                        const float* __restrict__ ad, float* __restrict__ ebuf,
                        float* __restrict__ m, int E, int NE) {
    int j = blockIdx.x * blockDim.x + threadIdx.x;
    if (j >= NE) return;
    int src, dst;
    if (j < E) {
        src = ei[j];
        dst = ei[E + j];
    } else {
        src = dst = j - E;
    }
    float e = as[src] + ad[dst];
    e = (e >= 0.0f) ? e : NEG_SLOPE * e;
    ebuf[j] = e;
    atomicMaxF(&m[dst], e);
}

// pass 2: w = exp(e - m[dst]); store w; denom[dst] += w
__global__ void edge2_k(const int* __restrict__ ei, const float* __restrict__ m,
                        float* __restrict__ ebuf, float* __restrict__ denom, int E, int NE) {
    int j = blockIdx.x * blockDim.x + threadIdx.x;
    if (j >= NE) return;
    int dst = (j < E) ? ei[E + j] : j - E;
    float w = expf(ebuf[j] - m[dst]);
    ebuf[j] = w;
    unsafeAtomicAdd(&denom[dst], w);
}

// pass 3 (wave per edge, lane=dim): out[dst,:] += h[src,:] * (w / (denom[dst]+eps))
__global__ void scatter_k(const int* __restrict__ ei, const float* __restrict__ ebuf,
                          const float* __restrict__ denom, const float* __restrict__ hsrc,
                          float* __restrict__ out, int E, int NE) {
    int wave = (int)((blockIdx.x * blockDim.x + threadIdx.x) >> 6);
    int lane = threadIdx.x & 63;
    if (wave >= NE) return;
    int src, dst;
    if (wave < E) {
        src = ei[wave];
        dst = ei[E + wave];
    } else {
        src = dst = wave - E;
    }
    float alpha = ebuf[wave] / (denom[dst] + 1e-16f);
    float v = hsrc[(size_t)src * HD + lane] * alpha;
    unsafeAtomicAdd(&out[(size_t)dst * HD + lane], v);
}

// one wave per graph: pooling (mean+max over sorted batch segment, applying final conv bias)
// then the 3-layer MLP, writing out[g]
__global__ void pool_mlp_k(const float* __restrict__ hfin, const float* __restrict__ hb,
                           const int* __restrict__ batch, int N,
                           const float* __restrict__ fc1W, const float* __restrict__ fc1b,
                           const float* __restrict__ fc2W, const float* __restrict__ fc2b,
                           const float* __restrict__ fc3W, const float* __restrict__ fc3b,
                           float* __restrict__ out) {
    __shared__ float lds[192];
    int g = blockIdx.x;
    int lane = threadIdx.x;
    // lower_bound(batch, g) and lower_bound(batch, g+1)
    int lo = 0, hi = N;
    while (lo < hi) {
        int mid = (lo + hi) >> 1;
        if (batch[mid] < g) lo = mid + 1; else hi = mid;
    }
    int start = lo;
    lo = start; hi = N;
    while (lo < hi) {
        int mid = (lo + hi) >> 1;
        if (batch[mid] < g + 1) lo = mid + 1; else hi = mid;
    }
    int end = lo;
    float bias = hb[lane];
    float sum = 0.0f, mx = -INFINITY;
    for (int n = start; n < end; n++) {
        float v = hfin[(size_t)n * HD + lane] + bias;
        sum += v;
        mx = fmaxf(mx, v);
    }
    int cnt = end - start;
    float mean = (cnt > 0) ? sum / (float)cnt : 0.0f;
    if (cnt == 0) mx = 0.0f;
    lds[lane] = mean;
    lds[64 + lane] = mx;
    __syncthreads();
    float o1 = fc1b[lane];
    for (int k = 0; k < 128; k++) o1 += lds[k] * fc1W[k * 64 + lane];
    o1 = fmaxf(o1, 0.0f);
    __syncthreads();
    lds[lane] = o1;
    __syncthreads();
    if (lane < 32) {
        float o2 = fc2b[lane];
        for (int k = 0; k < 64; k++) o2 += lds[k] * fc2W[k * 32 + lane];
        lds[128 + lane] = fmaxf(o2, 0.0f);
    }
    __syncthreads();
    if (lane == 0) {
        float o3 = fc3b[0];
        for (int k = 0; k < 32; k++) o3 += lds[128 + k] * fc3W[k];
        out[g] = o3;
    }
}

static inline size_t align256(size_t x) { return (x + 255) & ~(size_t)255; }

extern "C" void kernel_launch(void* const* d_in, const int* in_sizes, int n_in,
                              void* d_out, int out_size, void* d_ws, size_t ws_size,
                              hipStream_t stream) {
    const float* x      = (const float*)d_in[0];
    const int*   ei     = (const int*)d_in[1];
    const int*   batch  = (const int*)d_in[2];
    const float* embW   = (const float*)d_in[3];
    const float* embB   = (const float*)d_in[4];
    const float* g1W    = (const float*)d_in[5];
    const float* g1as   = (const float*)d_in[6];
    const float* g1ad   = (const float*)d_in[7];
    const float* g1b    = (const float*)d_in[8];
    const float* g2W    = (const float*)d_in[9];
    const float* g2as   = (const float*)d_in[10];
    const float* g2ad   = (const float*)d_in[11];
    const float* g2b    = (const float*)d_in[12];
    const float* fc1W   = (const float*)d_in[13];
    const float* fc1b   = (const float*)d_in[14];
    const float* fc2W   = (const float*)d_in[15];
    const float* fc2b   = (const float*)d_in[16];
    const float* fc3W   = (const float*)d_in[17];
    const float* fc3b   = (const float*)d_in[18];
    float* out = (float*)d_out;

    const int N  = in_sizes[0] / NODE_DIM;   // 200000
    const int E  = in_sizes[1] / 2;          // 1200000
    const int G  = out_size;                 // 2048
    const int NE = E + N;                    // edges incl. self-loops
    const int NH = N * HD;

    char* ws = (char*)d_ws;
    float* bufA   = (float*)ws; ws += align256((size_t)NH * 4);
    float* bufB   = (float*)ws; ws += align256((size_t)NH * 4);
    float* as_buf = (float*)ws; ws += align256((size_t)N * 4);
    float* ad_buf = (float*)ws; ws += align256((size_t)N * 4);
    float* m_buf  = (float*)ws; ws += align256((size_t)N * 4);
    float* dn_buf = (float*)ws; ws += align256((size_t)N * 4);
    float* e_buf  = (float*)ws; ws += align256((size_t)NE * 4);

    const int B = 256;
    dim3 blk(B);
    dim3 gr_elem((NH + B - 1) / B);          // element-grid over N*64
    dim3 gr_node((N * 64 + B - 1) / B);      // wave-per-node
    dim3 gr_edge((NE + B - 1) / B);          // thread-per-edge
    dim3 gr_scat(((size_t)NE * 64 + B - 1) / B); // wave-per-edge

    // ---- embed: bufA = x @ embW + embB
    embed_k<<<gr_elem, blk, 0, stream>>>(x, embW, embB, bufA, N);

    // ======== GAT layer 1 ========
    gemm_alpha_k<false><<<gr_node, blk, 0, stream>>>(bufA, nullptr, g1W, g1as, g1ad,
                                                     bufB, as_buf, ad_buf, N);
    init_k<<<gr_elem, blk, 0, stream>>>(bufA, m_buf, dn_buf, NH, N);
    edge1_k<<<gr_edge, blk, 0, stream>>>(ei, as_buf, ad_buf, e_buf, m_buf, E, NE);
    edge2_k<<<gr_edge, blk, 0, stream>>>(ei, m_buf, e_buf, dn_buf, E, NE);
    scatter_k<<<gr_scat, blk, 0, stream>>>(ei, e_buf, dn_buf, bufB, bufA, E, NE);
    // bufA now holds conv1 raw accumulation (bias g1b + relu applied lazily below)

    // ======== GAT layer 2 ========
    gemm_alpha_k<true><<<gr_node, blk, 0, stream>>>(bufA, g1b, g2W, g2as, g2ad,
                                                    bufB, as_buf, ad_buf, N);
    init_k<<<gr_elem, blk, 0, stream>>>(bufA, m_buf, dn_buf, NH, N);
    edge1_k<<<gr_edge, blk, 0, stream>>>(ei, as_buf, ad_buf, e_buf, m_buf, E, NE);
    edge2_k<<<gr_edge, blk, 0, stream>>>(ei, m_buf, e_buf, dn_buf, E, NE);
    scatter_k<<<gr_scat, blk, 0, stream>>>(ei, e_buf, dn_buf, bufB, bufA, E, NE);
    // bufA now holds conv2 raw accumulation (bias g2b applied lazily in pooling)

    // ---- pooling + MLP (one wave per graph)
    pool_mlp_k<<<dim3(G), dim3(64), 0, stream>>>(bufA, g2b, batch, N,
                                                 fc1W, fc1b, fc2W, fc2b, fc3W, fc3b, out);
}

// Round 2
// 928.034 us; speedup vs baseline: 1.4517x; 1.4517x over previous
//
#include <hip/hip_runtime.h>
#include <hip/hip_bf16.h>

#define HD 64
#define NODE_DIM 5
#define NEG_SLOPE 0.2f
#define SCAN_B 1024

// h0[n,d] = sum_k x[n,k]*W[k,d] + b[d]
__global__ void embed_k(const float* __restrict__ x, const float* __restrict__ W,
                        const float* __restrict__ b, float* __restrict__ h, int N) {
    int idx = blockIdx.x * blockDim.x + threadIdx.x;
    if (idx >= N * HD) return;
    int n = idx >> 6, d = idx & 63;
    float acc = b[d];
#pragma unroll
    for (int k = 0; k < NODE_DIM; k++) acc += x[n * NODE_DIM + k] * W[k * HD + d];
    h[idx] = acc;
}

// wave-per-node: hout[n,:] = pre(hin[n,:]) @ W ; alpha_s[n]=hout.a_src ; alpha_d[n]=hout.a_dst
template <bool PRE>
__global__ void gemm_alpha_k(const float* __restrict__ hin, const float* __restrict__ preb,
                             const float* __restrict__ W, const float* __restrict__ asrc,
                             const float* __restrict__ adst, float* __restrict__ hout,
                             float* __restrict__ alpha_s, float* __restrict__ alpha_d, int N) {
    int wave = (int)((blockIdx.x * blockDim.x + threadIdx.x) >> 6);
    int lane = threadIdx.x & 63;
    if (wave >= N) return;
    float hv = hin[(size_t)wave * HD + lane];
    if (PRE) hv = fmaxf(hv + preb[lane], 0.0f);
    float acc = 0.0f;
#pragma unroll
    for (int k = 0; k < HD; k++) {
        acc += __shfl(hv, k) * W[k * HD + lane];
    }
    hout[(size_t)wave * HD + lane] = acc;
    float ps = acc * asrc[lane];
    float pd = acc * adst[lane];
#pragma unroll
    for (int off = 32; off; off >>= 1) {
        ps += __shfl_xor(ps, off);
        pd += __shfl_xor(pd, off);
    }
    if (lane == 0) {
        alpha_s[wave] = ps;
        alpha_d[wave] = pd;
    }
}

// ---------------- CSR build (by dst, self-loops included) ----------------

__global__ void zero_deg_k(int* __restrict__ deg, int N) {
    int i = blockIdx.x * blockDim.x + threadIdx.x;
    if (i < N) deg[i] = 0;
}

__global__ void hist_k(const int* __restrict__ ei, int* __restrict__ deg, int E, int NE) {
    int j = blockIdx.x * blockDim.x + threadIdx.x;
    if (j >= NE) return;
    int dst = (j < E) ? ei[E + j] : j - E;
    atomicAdd(&deg[dst], 1);
}

// inclusive scan of deg per 1024-tile; tile result -> off[gid+1]; tile total -> blksum
__global__ void scan1_k(const int* __restrict__ deg, int* __restrict__ off,
                        int* __restrict__ blksum, int N) {
    __shared__ int s[SCAN_B];
    int gid = blockIdx.x * SCAN_B + threadIdx.x;
    int v = (gid < N) ? deg[gid] : 0;
    s[threadIdx.x] = v;
    __syncthreads();
#pragma unroll
    for (int o = 1; o < SCAN_B; o <<= 1) {
        int t = (threadIdx.x >= o) ? s[threadIdx.x - o] : 0;
        __syncthreads();
        s[threadIdx.x] += t;
        __syncthreads();
    }
    if (gid < N) off[gid + 1] = s[threadIdx.x];
    if (threadIdx.x == SCAN_B - 1) blksum[blockIdx.x] = s[SCAN_B - 1];
}

// single block: blksum -> exclusive prefix (nb <= 1024)
__global__ void scan2_k(int* __restrict__ blksum, int nb) {
    __shared__ int s[SCAN_B];
    int v = ((int)threadIdx.x < nb) ? blksum[threadIdx.x] : 0;
    s[threadIdx.x] = v;
    __syncthreads();
#pragma unroll
    for (int o = 1; o < SCAN_B; o <<= 1) {
        int t = (threadIdx.x >= o) ? s[threadIdx.x - o] : 0;
        __syncthreads();
        s[threadIdx.x] += t;
        __syncthreads();
    }
    if ((int)threadIdx.x < nb) blksum[threadIdx.x] = s[threadIdx.x] - v;  // exclusive
}

// off[gid+1] += blk prefix ; cursor[gid] = exclusive offset ; off[0] = 0
__global__ void scan3_k(int* __restrict__ off, const int* __restrict__ deg,
                        const int* __restrict__ blksum, int* __restrict__ cursor, int N) {
    int gid = blockIdx.x * blockDim.x + threadIdx.x;
    if (gid >= N) return;
    int inc = off[gid + 1] + blksum[gid >> 10];
    off[gid + 1] = inc;
    cursor[gid] = inc - deg[gid];
    if (gid == 0) off[0] = 0;
}

__global__ void fill_csr_k(const int* __restrict__ ei, int* __restrict__ cursor,
                           int* __restrict__ csr_src, int E, int NE) {
    int j = blockIdx.x * blockDim.x + threadIdx.x;
    if (j >= NE) return;
    int src, dst;
    if (j < E) { src = ei[j]; dst = ei[E + j]; }
    else       { src = dst = j - E; }
    int pos = atomicAdd(&cursor[dst], 1);
    csr_src[pos] = src;
}

// ---------------- fused per-node online-softmax aggregation ----------------
// wave per dst node, lane = feature dim. One pass over in-edges.
__global__ void aggregate_k(const int* __restrict__ off, const int* __restrict__ csr_src,
                            const float* __restrict__ as, const float* __restrict__ ad,
                            const float* __restrict__ h, float* __restrict__ out, int N) {
    int wave = (int)((blockIdx.x * blockDim.x + threadIdx.x) >> 6);
    int lane = threadIdx.x & 63;
    if (wave >= N) return;
    int s0 = off[wave], s1 = off[wave + 1];
    float adv = ad[wave];
    float m = -INFINITY, l = 0.0f, acc = 0.0f;
    for (int i = s0; i < s1; i++) {
        int src = csr_src[i];
        float e = as[src] + adv;
        e = (e >= 0.0f) ? e : NEG_SLOPE * e;
        float mn = fmaxf(m, e);
        float sc = __expf(m - mn);   // exp(-inf)=0 on first iter
        float we = __expf(e - mn);
        l = l * sc + we;
        acc = acc * sc + we * h[(size_t)src * HD + lane];
        m = mn;
    }
    out[(size_t)wave * HD + lane] = acc / (l + 1e-16f);
}

// one wave per graph: pooling + 3-layer MLP
__global__ void pool_mlp_k(const float* __restrict__ hfin, const float* __restrict__ hb,
                           const int* __restrict__ batch, int N,
                           const float* __restrict__ fc1W, const float* __restrict__ fc1b,
                           const float* __restrict__ fc2W, const float* __restrict__ fc2b,
                           const float* __restrict__ fc3W, const float* __restrict__ fc3b,
                           float* __restrict__ out) {
    __shared__ float lds[192];
    int g = blockIdx.x;
    int lane = threadIdx.x;
    int lo = 0, hi = N;
    while (lo < hi) { int mid = (lo + hi) >> 1; if (batch[mid] < g) lo = mid + 1; else hi = mid; }
    int start = lo;
    lo = start; hi = N;
    while (lo < hi) { int mid = (lo + hi) >> 1; if (batch[mid] < g + 1) lo = mid + 1; else hi = mid; }
    int end = lo;
    float bias = hb[lane];
    float sum = 0.0f, mx = -INFINITY;
    for (int n = start; n < end; n++) {
        float v = hfin[(size_t)n * HD + lane] + bias;
        sum += v;
        mx = fmaxf(mx, v);
    }
    int cnt = end - start;
    float mean = (cnt > 0) ? sum / (float)cnt : 0.0f;
    if (cnt == 0) mx = 0.0f;
    lds[lane] = mean;
    lds[64 + lane] = mx;
    __syncthreads();
    float o1 = fc1b[lane];
    for (int k = 0; k < 128; k++) o1 += lds[k] * fc1W[k * 64 + lane];
    o1 = fmaxf(o1, 0.0f);
    __syncthreads();
    lds[lane] = o1;
    __syncthreads();
    if (lane < 32) {
        float o2 = fc2b[lane];
        for (int k = 0; k < 64; k++) o2 += lds[k] * fc2W[k * 32 + lane];
        lds[128 + lane] = fmaxf(o2, 0.0f);
    }
    __syncthreads();
    if (lane == 0) {
        float o3 = fc3b[0];
        for (int k = 0; k < 32; k++) o3 += lds[128 + k] * fc3W[k];
        out[g] = o3;
    }
}

static inline size_t align256(size_t x) { return (x + 255) & ~(size_t)255; }

extern "C" void kernel_launch(void* const* d_in, const int* in_sizes, int n_in,
                              void* d_out, int out_size, void* d_ws, size_t ws_size,
                              hipStream_t stream) {
    const float* x      = (const float*)d_in[0];
    const int*   ei     = (const int*)d_in[1];
    const int*   batch  = (const int*)d_in[2];
    const float* embW   = (const float*)d_in[3];
    const float* embB   = (const float*)d_in[4];
    const float* g1W    = (const float*)d_in[5];
    const float* g1as   = (const float*)d_in[6];
    const float* g1ad   = (const float*)d_in[7];
    const float* g1b    = (const float*)d_in[8];
    const float* g2W    = (const float*)d_in[9];
    const float* g2as   = (const float*)d_in[10];
    const float* g2ad   = (const float*)d_in[11];
    const float* g2b    = (const float*)d_in[12];
    const float* fc1W   = (const float*)d_in[13];
    const float* fc1b   = (const float*)d_in[14];
    const float* fc2W   = (const float*)d_in[15];
    const float* fc2b   = (const float*)d_in[16];
    const float* fc3W   = (const float*)d_in[17];
    const float* fc3b   = (const float*)d_in[18];
    float* out = (float*)d_out;

    const int N  = in_sizes[0] / NODE_DIM;   // 200000
    const int E  = in_sizes[1] / 2;          // 1200000
    const int G  = out_size;                 // 2048
    const int NE = E + N;
    const int NH = N * HD;

    char* ws = (char*)d_ws;
    float* bufA   = (float*)ws; ws += align256((size_t)NH * 4);
    float* bufB   = (float*)ws; ws += align256((size_t)NH * 4);
    float* as_buf = (float*)ws; ws += align256((size_t)N * 4);
    float* ad_buf = (float*)ws; ws += align256((size_t)N * 4);
    int*   deg    = (int*)ws;   ws += align256((size_t)N * 4);
    int*   off    = (int*)ws;   ws += align256((size_t)(N + 1) * 4);
    int*   cursor = (int*)ws;   ws += align256((size_t)N * 4);
    int*   blksum = (int*)ws;   ws += align256((size_t)SCAN_B * 4);
    int*   csrsrc = (int*)ws;   ws += align256((size_t)NE * 4);

    const int B = 256;
    dim3 blk(B);
    dim3 gr_elem((NH + B - 1) / B);
    dim3 gr_node((N * 64 + B - 1) / B);      // wave-per-node
    dim3 gr_edge((NE + B - 1) / B);          // thread-per-edge
    dim3 gr_n((N + B - 1) / B);
    const int nb = (N + SCAN_B - 1) / SCAN_B;

    // ---- embed
    embed_k<<<gr_elem, blk, 0, stream>>>(x, embW, embB, bufA, N);

    // ---- CSR build (once, shared by both layers)
    zero_deg_k<<<gr_n, blk, 0, stream>>>(deg, N);
    hist_k<<<gr_edge, blk, 0, stream>>>(ei, deg, E, NE);
    scan1_k<<<dim3(nb), dim3(SCAN_B), 0, stream>>>(deg, off, blksum, N);
    scan2_k<<<dim3(1), dim3(SCAN_B), 0, stream>>>(blksum, nb);
    scan3_k<<<gr_n, blk, 0, stream>>>(off, deg, blksum, cursor, N);
    fill_csr_k<<<gr_edge, blk, 0, stream>>>(ei, cursor, csrsrc, E, NE);

    // ======== GAT layer 1 ========
    gemm_alpha_k<false><<<gr_node, blk, 0, stream>>>(bufA, nullptr, g1W, g1as, g1ad,
                                                     bufB, as_buf, ad_buf, N);
    aggregate_k<<<gr_node, blk, 0, stream>>>(off, csrsrc, as_buf, ad_buf, bufB, bufA, N);

    // ======== GAT layer 2 ========
    gemm_alpha_k<true><<<gr_node, blk, 0, stream>>>(bufA, g1b, g2W, g2as, g2ad,
                                                    bufB, as_buf, ad_buf, N);
    aggregate_k<<<gr_node, blk, 0, stream>>>(off, csrsrc, as_buf, ad_buf, bufB, bufA, N);

    // ---- pooling + MLP
    pool_mlp_k<<<dim3(G), dim3(64), 0, stream>>>(bufA, g2b, batch, N,
                                                 fc1W, fc1b, fc2W, fc2b, fc3W, fc3b, out);
}

// Round 3
// 811.783 us; speedup vs baseline: 1.6596x; 1.1432x over previous
//
#include <hip/hip_runtime.h>
#include <hip/hip_bf16.h>

#define HD 64
#define NODE_DIM 5
#define NEG_SLOPE 0.2f
#define SCAN_B 1024

// h0[n,d] = sum_k x[n,k]*W[k,d] + b[d]
__global__ void embed_k(const float* __restrict__ x, const float* __restrict__ W,
                        const float* __restrict__ b, float* __restrict__ h, int N) {
    int idx = blockIdx.x * blockDim.x + threadIdx.x;
    if (idx >= N * HD) return;
    int n = idx >> 6, d = idx & 63;
    float acc = b[d];
#pragma unroll
    for (int k = 0; k < NODE_DIM; k++) acc += x[n * NODE_DIM + k] * W[k * HD + d];
    h[idx] = acc;
}

// wave computes 8 nodes x 64 dims: hout[n,:] = hin[n,:] @ W, plus
// alpha_s[n] = hout[n,:].asrc, alpha_d[n] = hout[n,:].adst.
// Node base made wave-uniform via readfirstlane so h-row loads become s_load
// (SMEM pipe); W column lives in 64 VGPRs/lane; inner loop = pure v_fmac with
// 8-way ILP.
__global__ __launch_bounds__(256) void gemm_alpha_k(
    const float* __restrict__ hin, const float* __restrict__ W,
    const float* __restrict__ asrc, const float* __restrict__ adst,
    float* __restrict__ hout, float* __restrict__ alpha_s,
    float* __restrict__ alpha_d, int N) {
    const int lane = threadIdx.x & 63;
    const int wl = __builtin_amdgcn_readfirstlane(threadIdx.x >> 6);
    const int wave = blockIdx.x * 4 + wl;          // uniform (SGPR)
    const int n0 = wave * 8;
    if (n0 >= N) return;

    float wreg[64];
#pragma unroll
    for (int k = 0; k < 64; k++) wreg[k] = W[k * HD + lane];
    const float av = asrc[lane], bv = adst[lane];

    float acc[8] = {0, 0, 0, 0, 0, 0, 0, 0};
    const float4* hb = (const float4*)(hin + (size_t)n0 * HD);  // uniform base

    if (n0 + 8 <= N) {
#pragma unroll
        for (int kk = 0; kk < 16; kk++) {
            float4 hv[8];
#pragma unroll
            for (int i = 0; i < 8; i++) hv[i] = hb[i * 16 + kk];
#pragma unroll
            for (int i = 0; i < 8; i++) {
                acc[i] = fmaf(hv[i].x, wreg[4 * kk + 0], acc[i]);
                acc[i] = fmaf(hv[i].y, wreg[4 * kk + 1], acc[i]);
                acc[i] = fmaf(hv[i].z, wreg[4 * kk + 2], acc[i]);
                acc[i] = fmaf(hv[i].w, wreg[4 * kk + 3], acc[i]);
            }
        }
    } else {
        for (int i = 0; i < 8 && n0 + i < N; i++) {
            float a = 0.0f;
#pragma unroll
            for (int kk = 0; kk < 16; kk++) {
                float4 hv = hb[i * 16 + kk];
                a = fmaf(hv.x, wreg[4 * kk + 0], a);
                a = fmaf(hv.y, wreg[4 * kk + 1], a);
                a = fmaf(hv.z, wreg[4 * kk + 2], a);
                a = fmaf(hv.w, wreg[4 * kk + 3], a);
            }
            acc[i] = a;
        }
    }

#pragma unroll
    for (int i = 0; i < 8; i++) {
        int n = n0 + i;
        if (n >= N) break;
        hout[(size_t)n * HD + lane] = acc[i];
        float ps = acc[i] * av;
        float pd = acc[i] * bv;
#pragma unroll
        for (int off = 32; off; off >>= 1) {
            ps += __shfl_xor(ps, off);
            pd += __shfl_xor(pd, off);
        }
        if (lane == 0) {
            alpha_s[n] = ps;
            alpha_d[n] = pd;
        }
    }
}

// ---------------- CSR build (by dst, self-loops included) ----------------

__global__ void zero_deg_k(int* __restrict__ deg, int N) {
    int i = blockIdx.x * blockDim.x + threadIdx.x;
    if (i < N) deg[i] = 0;
}

__global__ void hist_k(const int* __restrict__ ei, int* __restrict__ deg, int E, int NE) {
    int j = blockIdx.x * blockDim.x + threadIdx.x;
    if (j >= NE) return;
    int dst = (j < E) ? ei[E + j] : j - E;
    atomicAdd(&deg[dst], 1);
}

__global__ void scan1_k(const int* __restrict__ deg, int* __restrict__ off,
                        int* __restrict__ blksum, int N) {
    __shared__ int s[SCAN_B];
    int gid = blockIdx.x * SCAN_B + threadIdx.x;
    int v = (gid < N) ? deg[gid] : 0;
    s[threadIdx.x] = v;
    __syncthreads();
#pragma unroll
    for (int o = 1; o < SCAN_B; o <<= 1) {
        int t = (threadIdx.x >= o) ? s[threadIdx.x - o] : 0;
        __syncthreads();
        s[threadIdx.x] += t;
        __syncthreads();
    }
    if (gid < N) off[gid + 1] = s[threadIdx.x];
    if (threadIdx.x == SCAN_B - 1) blksum[blockIdx.x] = s[SCAN_B - 1];
}

__global__ void scan2_k(int* __restrict__ blksum, int nb) {
    __shared__ int s[SCAN_B];
    int v = ((int)threadIdx.x < nb) ? blksum[threadIdx.x] : 0;
    s[threadIdx.x] = v;
    __syncthreads();
#pragma unroll
    for (int o = 1; o < SCAN_B; o <<= 1) {
        int t = (threadIdx.x >= o) ? s[threadIdx.x - o] : 0;
        __syncthreads();
        s[threadIdx.x] += t;
        __syncthreads();
    }
    if ((int)threadIdx.x < nb) blksum[threadIdx.x] = s[threadIdx.x] - v;  // exclusive
}

__global__ void scan3_k(int* __restrict__ off, const int* __restrict__ deg,
                        const int* __restrict__ blksum, int* __restrict__ cursor, int N) {
    int gid = blockIdx.x * blockDim.x + threadIdx.x;
    if (gid >= N) return;
    int inc = off[gid + 1] + blksum[gid >> 10];
    off[gid + 1] = inc;
    cursor[gid] = inc - deg[gid];
    if (gid == 0) off[0] = 0;
}

__global__ void fill_csr_k(const int* __restrict__ ei, int* __restrict__ cursor,
                           int* __restrict__ csr_src, int E, int NE) {
    int j = blockIdx.x * blockDim.x + threadIdx.x;
    if (j >= NE) return;
    int src, dst;
    if (j < E) { src = ei[j]; dst = ei[E + j]; }
    else       { src = dst = j - E; }
    int pos = atomicAdd(&cursor[dst], 1);
    csr_src[pos] = src;
}

// ---------------- fused per-node online-softmax aggregation ----------------
// wave per dst node, lane = feature dim. BR: apply bias+relu at store (fused
// epilogue of layer 1).
template <bool BR>
__global__ void aggregate_k(const int* __restrict__ off, const int* __restrict__ csr_src,
                            const float* __restrict__ as, const float* __restrict__ ad,
                            const float* __restrict__ h, const float* __restrict__ bias,
                            float* __restrict__ out, int N) {
    int wave = (int)((blockIdx.x * blockDim.x + threadIdx.x) >> 6);
    int lane = threadIdx.x & 63;
    if (wave >= N) return;
    int s0 = off[wave], s1 = off[wave + 1];
    float adv = ad[wave];
    float m = -INFINITY, l = 0.0f, acc = 0.0f;
    for (int i = s0; i < s1; i++) {
        int src = csr_src[i];
        float e = as[src] + adv;
        e = (e >= 0.0f) ? e : NEG_SLOPE * e;
        float mn = fmaxf(m, e);
        float sc = __expf(m - mn);   // exp(-inf)=0 on first iter
        float we = __expf(e - mn);
        l = l * sc + we;
        acc = acc * sc + we * h[(size_t)src * HD + lane];
        m = mn;
    }
    float r = acc / (l + 1e-16f);
    if (BR) r = fmaxf(r + bias[lane], 0.0f);
    out[(size_t)wave * HD + lane] = r;
}

// one wave per graph: pooling + 3-layer MLP
__global__ void pool_mlp_k(const float* __restrict__ hfin, const float* __restrict__ hb,
                           const int* __restrict__ batch, int N,
                           const float* __restrict__ fc1W, const float* __restrict__ fc1b,
                           const float* __restrict__ fc2W, const float* __restrict__ fc2b,
                           const float* __restrict__ fc3W, const float* __restrict__ fc3b,
                           float* __restrict__ out) {
    __shared__ float lds[192];
    int g = blockIdx.x;
    int lane = threadIdx.x;
    int lo = 0, hi = N;
    while (lo < hi) { int mid = (lo + hi) >> 1; if (batch[mid] < g) lo = mid + 1; else hi = mid; }
    int start = lo;
    lo = start; hi = N;
    while (lo < hi) { int mid = (lo + hi) >> 1; if (batch[mid] < g + 1) lo = mid + 1; else hi = mid; }
    int end = lo;
    float bias = hb[lane];
    float sum = 0.0f, mx = -INFINITY;
    for (int n = start; n < end; n++) {
        float v = hfin[(size_t)n * HD + lane] + bias;
        sum += v;
        mx = fmaxf(mx, v);
    }
    int cnt = end - start;
    float mean = (cnt > 0) ? sum / (float)cnt : 0.0f;
    if (cnt == 0) mx = 0.0f;
    lds[lane] = mean;
    lds[64 + lane] = mx;
    __syncthreads();
    float o1 = fc1b[lane];
    for (int k = 0; k < 128; k++) o1 += lds[k] * fc1W[k * 64 + lane];
    o1 = fmaxf(o1, 0.0f);
    __syncthreads();
    lds[lane] = o1;
    __syncthreads();
    if (lane < 32) {
        float o2 = fc2b[lane];
        for (int k = 0; k < 64; k++) o2 += lds[k] * fc2W[k * 32 + lane];
        lds[128 + lane] = fmaxf(o2, 0.0f);
    }
    __syncthreads();
    if (lane == 0) {
        float o3 = fc3b[0];
        for (int k = 0; k < 32; k++) o3 += lds[128 + k] * fc3W[k];
        out[g] = o3;
    }
}

static inline size_t align256(size_t x) { return (x + 255) & ~(size_t)255; }

extern "C" void kernel_launch(void* const* d_in, const int* in_sizes, int n_in,
                              void* d_out, int out_size, void* d_ws, size_t ws_size,
                              hipStream_t stream) {
    const float* x      = (const float*)d_in[0];
    const int*   ei     = (const int*)d_in[1];
    const int*   batch  = (const int*)d_in[2];
    const float* embW   = (const float*)d_in[3];
    const float* embB   = (const float*)d_in[4];
    const float* g1W    = (const float*)d_in[5];
    const float* g1as   = (const float*)d_in[6];
    const float* g1ad   = (const float*)d_in[7];
    const float* g1b    = (const float*)d_in[8];
    const float* g2W    = (const float*)d_in[9];
    const float* g2as   = (const float*)d_in[10];
    const float* g2ad   = (const float*)d_in[11];
    const float* g2b    = (const float*)d_in[12];
    const float* fc1W   = (const float*)d_in[13];
    const float* fc1b   = (const float*)d_in[14];
    const float* fc2W   = (const float*)d_in[15];
    const float* fc2b   = (const float*)d_in[16];
    const float* fc3W   = (const float*)d_in[17];
    const float* fc3b   = (const float*)d_in[18];
    float* out = (float*)d_out;

    const int N  = in_sizes[0] / NODE_DIM;   // 200000
    const int E  = in_sizes[1] / 2;          // 1200000
    const int G  = out_size;                 // 2048
    const int NE = E + N;
    const int NH = N * HD;

    char* ws = (char*)d_ws;
    float* bufA   = (float*)ws; ws += align256((size_t)NH * 4);
    float* bufB   = (float*)ws; ws += align256((size_t)NH * 4);
    float* as_buf = (float*)ws; ws += align256((size_t)N * 4);
    float* ad_buf = (float*)ws; ws += align256((size_t)N * 4);
    int*   deg    = (int*)ws;   ws += align256((size_t)N * 4);
    int*   off    = (int*)ws;   ws += align256((size_t)(N + 1) * 4);
    int*   cursor = (int*)ws;   ws += align256((size_t)N * 4);
    int*   blksum = (int*)ws;   ws += align256((size_t)SCAN_B * 4);
    int*   csrsrc = (int*)ws;   ws += align256((size_t)NE * 4);

    const int B = 256;
    dim3 blk(B);
    dim3 gr_elem((NH + B - 1) / B);
    dim3 gr_node((N * 64 + B - 1) / B);          // wave-per-node
    dim3 gr_gemm(((N + 7) / 8 + 3) / 4);         // wave-per-8-nodes, 4 waves/block
    dim3 gr_edge((NE + B - 1) / B);
    dim3 gr_n((N + B - 1) / B);
    const int nb = (N + SCAN_B - 1) / SCAN_B;

    // ---- embed
    embed_k<<<gr_elem, blk, 0, stream>>>(x, embW, embB, bufA, N);

    // ---- CSR build (once, shared by both layers)
    zero_deg_k<<<gr_n, blk, 0, stream>>>(deg, N);
    hist_k<<<gr_edge, blk, 0, stream>>>(ei, deg, E, NE);
    scan1_k<<<dim3(nb), dim3(SCAN_B), 0, stream>>>(deg, off, blksum, N);
    scan2_k<<<dim3(1), dim3(SCAN_B), 0, stream>>>(blksum, nb);
    scan3_k<<<gr_n, blk, 0, stream>>>(off, deg, blksum, cursor, N);
    fill_csr_k<<<gr_edge, blk, 0, stream>>>(ei, cursor, csrsrc, E, NE);

    // ======== GAT layer 1 ========
    gemm_alpha_k<<<gr_gemm, blk, 0, stream>>>(bufA, g1W, g1as, g1ad,
                                              bufB, as_buf, ad_buf, N);
    // aggregate with fused g1 bias + relu
    aggregate_k<true><<<gr_node, blk, 0, stream>>>(off, csrsrc, as_buf, ad_buf, bufB,
                                                   g1b, bufA, N);

    // ======== GAT layer 2 ========
    gemm_alpha_k<<<gr_gemm, blk, 0, stream>>>(bufA, g2W, g2as, g2ad,
                                              bufB, as_buf, ad_buf, N);
    aggregate_k<false><<<gr_node, blk, 0, stream>>>(off, csrsrc, as_buf, ad_buf, bufB,
                                                    nullptr, bufA, N);

    // ---- pooling + MLP (g2 bias applied here)
    pool_mlp_k<<<dim3(G), dim3(64), 0, stream>>>(bufA, g2b, batch, N,
                                                 fc1W, fc1b, fc2W, fc2b, fc3W, fc3b, out);
}

// Round 4
// 666.814 us; speedup vs baseline: 2.0204x; 1.2174x over previous
//
#include <hip/hip_runtime.h>
#include <hip/hip_bf16.h>

#define HD 64
#define NODE_DIM 5
#define NEG_SLOPE 0.2f
#define SCAN_B 1024

// h0[n,d] = sum_k x[n,k]*W[k,d] + b[d]
__global__ void embed_k(const float* __restrict__ x, const float* __restrict__ W,
                        const float* __restrict__ b, float* __restrict__ h, int N) {
    int idx = blockIdx.x * blockDim.x + threadIdx.x;
    if (idx >= N * HD) return;
    int n = idx >> 6, d = idx & 63;
    float acc = b[d];
#pragma unroll
    for (int k = 0; k < NODE_DIM; k++) acc += x[n * NODE_DIM + k] * W[k * HD + d];
    h[idx] = acc;
}

// wave computes 8 nodes x 64 dims: hout[n,:] = hin[n,:] @ W, plus
// alpha_s[n] = hout[n,:].asrc, alpha_d[n] = hout[n,:].adst.
__global__ __launch_bounds__(256) void gemm_alpha_k(
    const float* __restrict__ hin, const float* __restrict__ W,
    const float* __restrict__ asrc, const float* __restrict__ adst,
    float* __restrict__ hout, float* __restrict__ alpha_s,
    float* __restrict__ alpha_d, int N) {
    const int lane = threadIdx.x & 63;
    const int wl = __builtin_amdgcn_readfirstlane(threadIdx.x >> 6);
    const int wave = blockIdx.x * 4 + wl;          // uniform (SGPR)
    const int n0 = wave * 8;
    if (n0 >= N) return;

    float wreg[64];
#pragma unroll
    for (int k = 0; k < 64; k++) wreg[k] = W[k * HD + lane];
    const float av = asrc[lane], bv = adst[lane];

    float acc[8] = {0, 0, 0, 0, 0, 0, 0, 0};
    const float4* hb = (const float4*)(hin + (size_t)n0 * HD);  // uniform base

    if (n0 + 8 <= N) {
#pragma unroll
        for (int kk = 0; kk < 16; kk++) {
            float4 hv[8];
#pragma unroll
            for (int i = 0; i < 8; i++) hv[i] = hb[i * 16 + kk];
#pragma unroll
            for (int i = 0; i < 8; i++) {
                acc[i] = fmaf(hv[i].x, wreg[4 * kk + 0], acc[i]);
                acc[i] = fmaf(hv[i].y, wreg[4 * kk + 1], acc[i]);
                acc[i] = fmaf(hv[i].z, wreg[4 * kk + 2], acc[i]);
                acc[i] = fmaf(hv[i].w, wreg[4 * kk + 3], acc[i]);
            }
        }
    } else {
        for (int i = 0; i < 8 && n0 + i < N; i++) {
            float a = 0.0f;
#pragma unroll
            for (int kk = 0; kk < 16; kk++) {
                float4 hv = hb[i * 16 + kk];
                a = fmaf(hv.x, wreg[4 * kk + 0], a);
                a = fmaf(hv.y, wreg[4 * kk + 1], a);
                a = fmaf(hv.z, wreg[4 * kk + 2], a);
                a = fmaf(hv.w, wreg[4 * kk + 3], a);
            }
            acc[i] = a;
        }
    }

#pragma unroll
    for (int i = 0; i < 8; i++) {
        int n = n0 + i;
        if (n >= N) break;
        hout[(size_t)n * HD + lane] = acc[i];
        float ps = acc[i] * av;
        float pd = acc[i] * bv;
#pragma unroll
        for (int off = 32; off; off >>= 1) {
            ps += __shfl_xor(ps, off);
            pd += __shfl_xor(pd, off);
        }
        if (lane == 0) {
            alpha_s[n] = ps;
            alpha_d[n] = pd;
        }
    }
}

// ---------------- CSR build (by dst, self-loops included) ----------------

__global__ void zero_deg_k(int* __restrict__ deg, int N) {
    int i = blockIdx.x * blockDim.x + threadIdx.x;
    if (i < N) deg[i] = 0;
}

__global__ void hist_k(const int* __restrict__ ei, int* __restrict__ deg, int E, int NE) {
    int j = blockIdx.x * blockDim.x + threadIdx.x;
    if (j >= NE) return;
    int dst = (j < E) ? ei[E + j] : j - E;
    atomicAdd(&deg[dst], 1);
}

__global__ void scan1_k(const int* __restrict__ deg, int* __restrict__ off,
                        int* __restrict__ blksum, int N) {
    __shared__ int s[SCAN_B];
    int gid = blockIdx.x * SCAN_B + threadIdx.x;
    int v = (gid < N) ? deg[gid] : 0;
    s[threadIdx.x] = v;
    __syncthreads();
#pragma unroll
    for (int o = 1; o < SCAN_B; o <<= 1) {
        int t = (threadIdx.x >= o) ? s[threadIdx.x - o] : 0;
        __syncthreads();
        s[threadIdx.x] += t;
        __syncthreads();
    }
    if (gid < N) off[gid + 1] = s[threadIdx.x];
    if (threadIdx.x == SCAN_B - 1) blksum[blockIdx.x] = s[SCAN_B - 1];
}

__global__ void scan2_k(int* __restrict__ blksum, int nb) {
    __shared__ int s[SCAN_B];
    int v = ((int)threadIdx.x < nb) ? blksum[threadIdx.x] : 0;
    s[threadIdx.x] = v;
    __syncthreads();
#pragma unroll
    for (int o = 1; o < SCAN_B; o <<= 1) {
        int t = (threadIdx.x >= o) ? s[threadIdx.x - o] : 0;
        __syncthreads();
        s[threadIdx.x] += t;
        __syncthreads();
    }
    if ((int)threadIdx.x < nb) blksum[threadIdx.x] = s[threadIdx.x] - v;  // exclusive
}

__global__ void scan3_k(int* __restrict__ off, const int* __restrict__ deg,
                        const int* __restrict__ blksum, int* __restrict__ cursor, int N) {
    int gid = blockIdx.x * blockDim.x + threadIdx.x;
    if (gid >= N) return;
    int inc = off[gid + 1] + blksum[gid >> 10];
    off[gid + 1] = inc;
    cursor[gid] = inc - deg[gid];
    if (gid == 0) off[0] = 0;
}

__global__ void fill_csr_k(const int* __restrict__ ei, int* __restrict__ cursor,
                           int* __restrict__ csr_src, int E, int NE) {
    int j = blockIdx.x * blockDim.x + threadIdx.x;
    if (j >= NE) return;
    int src, dst;
    if (j < E) { src = ei[j]; dst = ei[E + j]; }
    else       { src = dst = j - E; }
    int pos = atomicAdd(&cursor[dst], 1);
    csr_src[pos] = src;
}

// ---------------- attention weights (scalar domain, thread-per-node) -------
// pass 1: exact max over in-edges; pass 2: w = exp(e-m) stored CSR-order,
// denom[n] = sum w. 64x less VALU than doing this in the wide kernel.
__global__ void attn_w_k(const int* __restrict__ off, const int* __restrict__ csr_src,
                         const float* __restrict__ as, const float* __restrict__ ad,
                         float* __restrict__ w, float* __restrict__ denom, int N) {
    int n = blockIdx.x * blockDim.x + threadIdx.x;
    if (n >= N) return;
    int s0 = off[n], s1 = off[n + 1];
    float adv = ad[n];
    float m = -INFINITY;
    for (int i = s0; i < s1; i++) {
        float e = as[csr_src[i]] + adv;
        e = (e >= 0.0f) ? e : NEG_SLOPE * e;
        m = fmaxf(m, e);
    }
    float dsum = 0.0f;
    for (int i = s0; i < s1; i++) {
        float e = as[csr_src[i]] + adv;
        e = (e >= 0.0f) ? e : NEG_SLOPE * e;
        float ww = __expf(e - m);
        w[i] = ww;
        dsum += ww;
    }
    denom[n] = dsum;
}

// ---------------- weighted gather ----------------
// wave = 4 nodes; 16 lanes/node; each lane holds 4 dims (float4).
// acc += w[i] * h[src]; divide by denom at end. BR: fused bias+relu epilogue.
template <bool BR>
__global__ __launch_bounds__(256) void gather_k(
    const int* __restrict__ off, const int* __restrict__ csr_src,
    const float* __restrict__ w, const float* __restrict__ denom,
    const float* __restrict__ h, const float* __restrict__ bias,
    float* __restrict__ out, int N) {
    int tid = blockIdx.x * blockDim.x + threadIdx.x;
    int wv = tid >> 6;
    int lane = threadIdx.x & 63;
    int grp = lane >> 4;   // node within wave
    int l16 = lane & 15;   // float4 index within row
    int n = wv * 4 + grp;
    if (n >= N) return;
    int s0 = off[n], s1 = off[n + 1];
    const float4* h4 = (const float4*)h;
    float4 acc0 = {0, 0, 0, 0}, acc1 = {0, 0, 0, 0};
    int i = s0;
    for (; i + 2 <= s1; i += 2) {
        int src0 = csr_src[i], src1 = csr_src[i + 1];
        float w0 = w[i], w1 = w[i + 1];
        float4 hv0 = h4[(size_t)src0 * 16 + l16];
        float4 hv1 = h4[(size_t)src1 * 16 + l16];
        acc0.x = fmaf(w0, hv0.x, acc0.x); acc0.y = fmaf(w0, hv0.y, acc0.y);
        acc0.z = fmaf(w0, hv0.z, acc0.z); acc0.w = fmaf(w0, hv0.w, acc0.w);
        acc1.x = fmaf(w1, hv1.x, acc1.x); acc1.y = fmaf(w1, hv1.y, acc1.y);
        acc1.z = fmaf(w1, hv1.z, acc1.z); acc1.w = fmaf(w1, hv1.w, acc1.w);
    }
    if (i < s1) {
        int src0 = csr_src[i];
        float w0 = w[i];
        float4 hv0 = h4[(size_t)src0 * 16 + l16];
        acc0.x = fmaf(w0, hv0.x, acc0.x); acc0.y = fmaf(w0, hv0.y, acc0.y);
        acc0.z = fmaf(w0, hv0.z, acc0.z); acc0.w = fmaf(w0, hv0.w, acc0.w);
    }
    float inv = 1.0f / (denom[n] + 1e-16f);
    float4 r;
    r.x = (acc0.x + acc1.x) * inv;
    r.y = (acc0.y + acc1.y) * inv;
    r.z = (acc0.z + acc1.z) * inv;
    r.w = (acc0.w + acc1.w) * inv;
    if (BR) {
        float4 b = ((const float4*)bias)[l16];
        r.x = fmaxf(r.x + b.x, 0.0f);
        r.y = fmaxf(r.y + b.y, 0.0f);
        r.z = fmaxf(r.z + b.z, 0.0f);
        r.w = fmaxf(r.w + b.w, 0.0f);
    }
    ((float4*)out)[(size_t)n * 16 + l16] = r;
}

// one wave per graph: pooling + 3-layer MLP
__global__ void pool_mlp_k(const float* __restrict__ hfin, const float* __restrict__ hb,
                           const int* __restrict__ batch, int N,
                           const float* __restrict__ fc1W, const float* __restrict__ fc1b,
                           const float* __restrict__ fc2W, const float* __restrict__ fc2b,
                           const float* __restrict__ fc3W, const float* __restrict__ fc3b,
                           float* __restrict__ out) {
    __shared__ float lds[192];
    int g = blockIdx.x;
    int lane = threadIdx.x;
    int lo = 0, hi = N;
    while (lo < hi) { int mid = (lo + hi) >> 1; if (batch[mid] < g) lo = mid + 1; else hi = mid; }
    int start = lo;
    lo = start; hi = N;
    while (lo < hi) { int mid = (lo + hi) >> 1; if (batch[mid] < g + 1) lo = mid + 1; else hi = mid; }
    int end = lo;
    float bias = hb[lane];
    float sum = 0.0f, mx = -INFINITY;
    for (int n = start; n < end; n++) {
        float v = hfin[(size_t)n * HD + lane] + bias;
        sum += v;
        mx = fmaxf(mx, v);
    }
    int cnt = end - start;
    float mean = (cnt > 0) ? sum / (float)cnt : 0.0f;
    if (cnt == 0) mx = 0.0f;
    lds[lane] = mean;
    lds[64 + lane] = mx;
    __syncthreads();
    float o1 = fc1b[lane];
    for (int k = 0; k < 128; k++) o1 += lds[k] * fc1W[k * 64 + lane];
    o1 = fmaxf(o1, 0.0f);
    __syncthreads();
    lds[lane] = o1;
    __syncthreads();
    if (lane < 32) {
        float o2 = fc2b[lane];
        for (int k = 0; k < 64; k++) o2 += lds[k] * fc2W[k * 32 + lane];
        lds[128 + lane] = fmaxf(o2, 0.0f);
    }
    __syncthreads();
    if (lane == 0) {
        float o3 = fc3b[0];
        for (int k = 0; k < 32; k++) o3 += lds[128 + k] * fc3W[k];
        out[g] = o3;
    }
}

static inline size_t align256(size_t x) { return (x + 255) & ~(size_t)255; }

extern "C" void kernel_launch(void* const* d_in, const int* in_sizes, int n_in,
                              void* d_out, int out_size, void* d_ws, size_t ws_size,
                              hipStream_t stream) {
    const float* x      = (const float*)d_in[0];
    const int*   ei     = (const int*)d_in[1];
    const int*   batch  = (const int*)d_in[2];
    const float* embW   = (const float*)d_in[3];
    const float* embB   = (const float*)d_in[4];
    const float* g1W    = (const float*)d_in[5];
    const float* g1as   = (const float*)d_in[6];
    const float* g1ad   = (const float*)d_in[7];
    const float* g1b    = (const float*)d_in[8];
    const float* g2W    = (const float*)d_in[9];
    const float* g2as   = (const float*)d_in[10];
    const float* g2ad   = (const float*)d_in[11];
    const float* g2b    = (const float*)d_in[12];
    const float* fc1W   = (const float*)d_in[13];
    const float* fc1b   = (const float*)d_in[14];
    const float* fc2W   = (const float*)d_in[15];
    const float* fc2b   = (const float*)d_in[16];
    const float* fc3W   = (const float*)d_in[17];
    const float* fc3b   = (const float*)d_in[18];
    float* out = (float*)d_out;

    const int N  = in_sizes[0] / NODE_DIM;   // 200000
    const int E  = in_sizes[1] / 2;          // 1200000
    const int G  = out_size;                 // 2048
    const int NE = E + N;
    const int NH = N * HD;

    char* ws = (char*)d_ws;
    float* bufA   = (float*)ws; ws += align256((size_t)NH * 4);
    float* bufB   = (float*)ws; ws += align256((size_t)NH * 4);
    float* as_buf = (float*)ws; ws += align256((size_t)N * 4);
    float* ad_buf = (float*)ws; ws += align256((size_t)N * 4);
    float* dn_buf = (float*)ws; ws += align256((size_t)N * 4);
    int*   deg    = (int*)ws;   ws += align256((size_t)N * 4);
    int*   off    = (int*)ws;   ws += align256((size_t)(N + 1) * 4);
    int*   cursor = (int*)ws;   ws += align256((size_t)N * 4);
    int*   blksum = (int*)ws;   ws += align256((size_t)SCAN_B * 4);
    int*   csrsrc = (int*)ws;   ws += align256((size_t)NE * 4);
    float* w_buf  = (float*)ws; ws += align256((size_t)NE * 4);

    const int B = 256;
    dim3 blk(B);
    dim3 gr_elem((NH + B - 1) / B);
    dim3 gr_gemm(((N + 7) / 8 + 3) / 4);         // wave-per-8-nodes, 4 waves/block
    dim3 gr_gath(((N + 3) / 4 * 64 + B - 1) / B); // wave-per-4-nodes
    dim3 gr_edge((NE + B - 1) / B);
    dim3 gr_n((N + B - 1) / B);
    const int nb = (N + SCAN_B - 1) / SCAN_B;

    // ---- embed
    embed_k<<<gr_elem, blk, 0, stream>>>(x, embW, embB, bufA, N);

    // ---- CSR build (once, shared by both layers)
    zero_deg_k<<<gr_n, blk, 0, stream>>>(deg, N);
    hist_k<<<gr_edge, blk, 0, stream>>>(ei, deg, E, NE);
    scan1_k<<<dim3(nb), dim3(SCAN_B), 0, stream>>>(deg, off, blksum, N);
    scan2_k<<<dim3(1), dim3(SCAN_B), 0, stream>>>(blksum, nb);
    scan3_k<<<gr_n, blk, 0, stream>>>(off, deg, blksum, cursor, N);
    fill_csr_k<<<gr_edge, blk, 0, stream>>>(ei, cursor, csrsrc, E, NE);

    // ======== GAT layer 1 ========
    gemm_alpha_k<<<gr_gemm, blk, 0, stream>>>(bufA, g1W, g1as, g1ad,
                                              bufB, as_buf, ad_buf, N);
    attn_w_k<<<gr_n, blk, 0, stream>>>(off, csrsrc, as_buf, ad_buf, w_buf, dn_buf, N);
    gather_k<true><<<gr_gath, blk, 0, stream>>>(off, csrsrc, w_buf, dn_buf, bufB,
                                                g1b, bufA, N);

    // ======== GAT layer 2 ========
    gemm_alpha_k<<<gr_gemm, blk, 0, stream>>>(bufA, g2W, g2as, g2ad,
                                              bufB, as_buf, ad_buf, N);
    attn_w_k<<<gr_n, blk, 0, stream>>>(off, csrsrc, as_buf, ad_buf, w_buf, dn_buf, N);
    gather_k<false><<<gr_gath, blk, 0, stream>>>(off, csrsrc, w_buf, dn_buf, bufB,
                                                 nullptr, bufA, N);

    // ---- pooling + MLP (g2 bias applied here)
    pool_mlp_k<<<dim3(G), dim3(64), 0, stream>>>(bufA, g2b, batch, N,
                                                 fc1W, fc1b, fc2W, fc2b, fc3W, fc3b, out);
}